// Round 7
// baseline (265.031 us; speedup 1.0000x reference)
//
#include <hip/hip_runtime.h>
#include <math.h>

// Problem constants (from reference init_kwargs)
#define NBATCH 32
#define NSEQ 512
#define NSAMP 8      // NUM_SAMPLES
#define NEXP 256     // NUM_EXP
#define KBOUND 40    // NUM_SAMPLES_BOUNDARY
#define NMARK 10     // NUM_MARK
#define DTIME_MAX 5.0f
#define OVER_SAMPLE 1.5f
#define NBS (NBATCH * NSEQ)   // 16384

typedef float f32x4 __attribute__((ext_vector_type(4)));

// cos(x) via 2-term Cody-Waite reduction in revolution space + v_cos_f32.
__device__ __forceinline__ float fast_cos(float x) {
    constexpr double inv2pi_d = 0.15915494309189535;
    constexpr float chi = (float)inv2pi_d;
    constexpr float clo = (float)(inv2pi_d - (double)chi);
    float n = rintf(x * chi);
    float f = fmaf(x, chi, -n);
    f = fmaf(x, clo, f);
    return __builtin_amdgcn_cosf(f);
}

// sum_m softplus(eb[m] + sc[m]*c) via log-product identity. Validated absmax=0.
__device__ __forceinline__ float intensity_sum(float c, const float eb[NMARK],
                                               const float sc[NMARK]) {
    const float NLOG2E = -1.4426950408889634f;
    const float LN2    =  0.69314718055994531f;
    float acc0 = 0.f, acc1 = 0.f, p0 = 1.f, p1 = 1.f;
    #pragma unroll
    for (int m = 0; m < NMARK; m += 2) {
        float x0 = fmaf(sc[m],     c, eb[m]);
        float x1 = fmaf(sc[m + 1], c, eb[m + 1]);
        float e0 = __builtin_amdgcn_exp2f(fabsf(x0) * NLOG2E);
        float e1 = __builtin_amdgcn_exp2f(fabsf(x1) * NLOG2E);
        p0 *= (1.f + e0);
        p1 *= (1.f + e1);
        acc0 += fmaxf(x0, 0.f);
        acc1 += fmaxf(x1, 0.f);
    }
    return fmaf(LN2, __builtin_amdgcn_logf(p0 * p1), acc0 + acc1);
}

__device__ __forceinline__ float rfl_f(float x) {
    return __int_as_float(__builtin_amdgcn_readfirstlane(__float_as_int(x)));
}

__device__ __forceinline__ f32x4 nt_load4(const float* p) {
    return __builtin_nontemporal_load(reinterpret_cast<const f32x4*>(p));
}

// One wave per (b,s). Early-exit rejection sampling:
// scan candidates in ascending expn order (batches of 8 smallest); the first
// resolving batch's min-over-accepted == global min-over-accepted (exact).
__global__ __launch_bounds__(256) void syn_event_sampler(
    const float* __restrict__ time_seq, const float* __restrict__ dt_seq,
    const int*   __restrict__ event_seq, const float* __restrict__ exp_raw,
    const float* __restrict__ unif, const float* __restrict__ emb,
    const float* __restrict__ scale, const float* __restrict__ bias,
    float* __restrict__ out_res, float* __restrict__ out_w)
{
    const int lane = threadIdx.x & 63;
    const int wv   = threadIdx.x >> 6;
    const int bs   = blockIdx.x * 4 + wv;

    // ---- wave-uniform scalars ----
    const float t   = rfl_f(time_seq[bs]);
    const float dtv = rfl_f(dt_seq[bs]);
    const int   ev  = __builtin_amdgcn_readfirstlane(event_seq[bs]);

    float eb[NMARK], sc[NMARK];
    #pragma unroll
    for (int m = 0; m < NMARK; ++m) {
        eb[m] = emb[ev * NMARK + m] + bias[m];
        sc[m] = scale[m];
    }

    // ---- upper bound (identical to validated path) ----
    float bsum = -INFINITY;
    if (lane < KBOUND) {
        const float step = 1.0f / 39.0f;
        float tb = __fadd_rn(t, __fmul_rn(dtv, __fmul_rn((float)lane, step)));
        bsum = intensity_sum(fast_cos(tb), eb, sc);
    }
    #pragma unroll
    for (int off = 1; off < 64; off <<= 1)
        bsum = fmaxf(bsum, __shfl_xor(bsum, off, 64));
    const float upper = bsum * OVER_SAMPLE;

    // ---- expn for all 256 candidates (bit-identical values) ----
    const f32x4 er4 = nt_load4(exp_raw + (size_t)bs * NEXP + 4 * lane);
    float ex0 = er4.x / upper, ex1 = er4.y / upper;
    float ex2 = er4.z / upper, ex3 = er4.w / upper;
    // working copy for extraction (consumed slots -> +inf)
    float w0 = ex0, w1 = ex1, w2 = ex2, w3 = ex3;

    const int   myns = lane >> 3;            // ns this lane serves (0..7)
    const int   myc  = lane & 7;             // candidate slot within batch
    const float* urow = unif + (size_t)bs * NSAMP * NEXP + (size_t)myns * NEXP;

    unsigned active = 0xFFu;                 // wave-uniform ns-active mask
    float resv = INFINITY;                   // group-uniform result for myns

    for (int round = 0; round < 32 && active; ++round) {
        // ---- extract 8 smallest remaining (unordered within batch) ----
        float myv = INFINITY; int myi = 0;
        #pragma unroll
        for (int c = 0; c < 8; ++c) {
            float lv = w0; int li = 0;
            if (w1 < lv) { lv = w1; li = 1; }
            if (w2 < lv) { lv = w2; li = 2; }
            if (w3 < lv) { lv = w3; li = 3; }
            li = lane * 4 + li;
            #pragma unroll
            for (int off = 1; off < 64; off <<= 1) {
                float pv = __shfl_xor(lv, off, 64);
                int   pi = __shfl_xor(li, off, 64);
                if (pv < lv || (pv == lv && pi < li)) { lv = pv; li = pi; }
            }
            if (myc == c) { myv = lv; myi = li; }       // no arrays (reg-safe)
            if ((li >> 2) == lane) {                     // owner clears slot
                int s = li & 3;
                if (s == 0) w0 = INFINITY;
                else if (s == 1) w1 = INFINITY;
                else if (s == 2) w2 = INFINITY;
                else w3 = INFINITY;
            }
        }
        // batch empty? (all remaining exhausted)
        if (__ballot(myv < INFINITY) == 0ull) break;

        // ---- totals for the 8 candidates (one intensity_sum wall-time) ----
        float tot = intensity_sum(fast_cos(t + myv), eb, sc); // NaN if myv=inf

        // ---- the only unif touches: 8 candidates x 8 ns, scattered 4B nt ----
        float u = __builtin_nontemporal_load(urow + myi);
        bool acc = (myv < INFINITY) && (__fmul_rn(u, upper) < tot);

        // min over accepted within this ns's 8 candidate-lanes
        float mv = acc ? myv : INFINITY;
        mv = fminf(mv, __shfl_xor(mv, 1, 64));
        mv = fminf(mv, __shfl_xor(mv, 2, 64));
        mv = fminf(mv, __shfl_xor(mv, 4, 64));

        bool ns_act = (active >> myns) & 1u;
        if (ns_act && mv < INFINITY) resv = mv;

        unsigned long long b = __ballot(ns_act && mv < INFINITY && myc == 0);
        unsigned res8 = 0;
        #pragma unroll
        for (int n = 0; n < 8; ++n)
            res8 |= (unsigned)((b >> (n * 8)) & 1ull) << n;
        active &= ~res8;
    }

    // ---- store: lane<8 takes group lane's resv ----
    float r = __shfl(resv, (lane & 7) * 8, 64);
    if (lane < NSAMP) {
        r = isinf(r) ? DTIME_MAX : r;
        r = fminf(r, 1e5f);
        out_res[(size_t)bs * NSAMP + lane] = r;
        out_w  [(size_t)bs * NSAMP + lane] = 1.0f / NSAMP;
    }
}

// Diagnostic: 3x streaming nt read of unif (402 MB logical) -> per-thread min.
// Slow enough to surface in rocprof top-5 with counters (if eff. BW < ~5 TB/s).
__global__ __launch_bounds__(256) void bw_probe(const float* __restrict__ unif,
                                                float* __restrict__ wsout)
{
    const size_t tid = (size_t)blockIdx.x * 256 + threadIdx.x;  // 524288 threads
    const size_t n4  = (size_t)NBS * NSAMP * NEXP / 4;          // 8.4M float4
    float acc = 1e30f;
    for (int rep = 0; rep < 3; ++rep) {
        for (size_t i = tid; i < n4; i += (size_t)2048 * 256) {
            f32x4 v = __builtin_nontemporal_load(
                reinterpret_cast<const f32x4*>(unif) + i);
            acc = fminf(acc, fminf(fminf(v.x, v.y), fminf(v.z, v.w)));
        }
    }
    wsout[tid] = acc;
}

extern "C" void kernel_launch(void* const* d_in, const int* in_sizes, int n_in,
                              void* d_out, int out_size, void* d_ws, size_t ws_size,
                              hipStream_t stream) {
    const float* time_seq = (const float*)d_in[0];
    const float* dt_seq   = (const float*)d_in[1];
    const int*   ev_seq   = (const int*)  d_in[2];
    const float* exp_raw  = (const float*)d_in[3];
    const float* unif     = (const float*)d_in[4];
    const float* emb      = (const float*)d_in[5];
    const float* scale    = (const float*)d_in[6];
    const float* bias     = (const float*)d_in[7];

    float* out_res = (float*)d_out;                          // [B,S,NSAMP]
    float* out_w   = out_res + (size_t)NBS * NSAMP;

    syn_event_sampler<<<dim3(NBS / 4), dim3(256), 0, stream>>>(
        time_seq, dt_seq, ev_seq, exp_raw, unif, emb, scale, bias, out_res, out_w);

    bw_probe<<<dim3(2048), dim3(256), 0, stream>>>(unif, (float*)d_ws);
}